// Round 8
// baseline (414.626 us; speedup 1.0000x reference)
//
#include <hip/hip_runtime.h>

#define NN 400000
#define NE 400000

typedef __attribute__((ext_vector_type(4))) float f32x4;
typedef __attribute__((ext_vector_type(8))) short s16x8;
typedef unsigned short ushort_t;

__device__ __forceinline__ ushort_t f2bf(float f) {
    union { float f; unsigned int u; } c;
    c.f = f;
    unsigned int u = c.u;
    u = u + 0x7fffu + ((u >> 16) & 1u);
    return (ushort_t)(u >> 16);
}
__device__ __forceinline__ float bf2f(ushort_t v) {
    union { unsigned int u; float f; } c;
    c.u = ((unsigned int)v) << 16;
    return c.f;
}

// --- detect whether edge_index arrived as int64 (odd 32-bit words all zero) ---
__global__ void k_detect(const int* __restrict__ ei_raw, int* __restrict__ flag) {
    if (threadIdx.x == 0 && blockIdx.x == 0) {
        int is64 = 1;
        for (int i = 0; i < 64; i++)
            if (ei_raw[2 * i + 1] != 0) { is64 = 0; break; }
        flag[0] = is64;
    }
}

__global__ void k_cvt_idx(const int* __restrict__ ei_raw, const int* __restrict__ flag,
                          int* __restrict__ ei32) {
    const int i = blockIdx.x * 256 + threadIdx.x;
    const int f = flag[0];
    ei32[i] = f ? ei_raw[2 * i] : ei_raw[i];
}

// --- W [128,512] f32 -> bf16, plain row-major ---
__global__ void k_wcvt(const float* __restrict__ W, ushort_t* __restrict__ wbf) {
    const int i = blockIdx.x * 256 + threadIdx.x;
    wbf[i] = f2bf(W[i]);
}

// --- fused: per-node u,v scores + x -> bf16 conversion (unchanged) ---
__global__ void k_uv_cvt(const float* __restrict__ x, const float* __restrict__ att,
                         ushort_t* __restrict__ xbf, float* __restrict__ uv) {
    const int lane = threadIdx.x & 63;
    const int wid = threadIdx.x >> 6;
    const int g = lane & 15;
    const int ns = lane >> 4;

    float areg[8][8];
#pragma unroll
    for (int h = 0; h < 4; h++) {
        const f32x4 fa = *(const f32x4*)(att + h * 256 + g * 8);
        const f32x4 fb = *(const f32x4*)(att + h * 256 + g * 8 + 4);
        const f32x4 ba = *(const f32x4*)(att + h * 256 + 128 + g * 8);
        const f32x4 bb = *(const f32x4*)(att + h * 256 + 128 + g * 8 + 4);
#pragma unroll
        for (int m = 0; m < 4; m++) {
            areg[h][m] = fa[m];     areg[h][4 + m] = fb[m];
            areg[4 + h][m] = ba[m]; areg[4 + h][4 + m] = bb[m];
        }
    }

    for (int tile = blockIdx.x; tile < NN / 32; tile += gridDim.x) {
        const int nb = tile * 32 + wid * 8 + ns;
#pragma unroll
        for (int t = 0; t < 2; t++) {
            const int n = nb + t * 4;
            const f32x4 xa = *(const f32x4*)(x + (size_t)n * 128 + g * 8);
            const f32x4 xb = *(const f32x4*)(x + (size_t)n * 128 + g * 8 + 4);
            s16x8 pk;
#pragma unroll
            for (int m = 0; m < 4; m++) { pk[m] = (short)f2bf(xa[m]); pk[4 + m] = (short)f2bf(xb[m]); }
            *(s16x8*)(xbf + (size_t)n * 128 + g * 8) = pk;
            float r[8];
#pragma unroll
            for (int v = 0; v < 8; v++) {
                float s = 0.f;
#pragma unroll
                for (int m = 0; m < 4; m++) s += xa[m] * areg[v][m];
#pragma unroll
                for (int m = 0; m < 4; m++) s += xb[m] * areg[v][4 + m];
                r[v] = s;
            }
#pragma unroll
            for (int mask = 1; mask <= 4; mask <<= 1)
#pragma unroll
                for (int v = 0; v < 8; v++) r[v] += __shfl_xor(r[v], mask, 64);
            const int gv = g & 7;
            float s = r[0];
#pragma unroll
            for (int v = 1; v < 8; v++) s = (gv == v) ? r[v] : s;
            s += __shfl_xor(s, 8, 64);
            if (g < 8) uv[(size_t)n * 8 + g] = s;
        }
    }
}

// --- per-edge: leaky_relu -> head softmax -> p=exp(score), atomic denom ---
__global__ void k_edge(const int* __restrict__ ei, const float* __restrict__ uv,
                       float* __restrict__ p, float* __restrict__ denom) {
    const int e = blockIdx.x * 256 + threadIdx.x;
    if (e >= NE) return;
    const int row = ei[e];
    const int col = ei[NE + e];
    const f32x4 u = *(const f32x4*)(uv + (size_t)row * 8);
    const f32x4 v = *(const f32x4*)(uv + (size_t)col * 8 + 4);
    float s[4];
    float mx = -1e30f;
#pragma unroll
    for (int h = 0; h < 4; h++) {
        float t = u[h] + v[h];
        t = t > 0.f ? t : 0.01f * t;
        s[h] = t;
        mx = fmaxf(mx, t);
    }
    float ex[4], sum = 0.f;
#pragma unroll
    for (int h = 0; h < 4; h++) { ex[h] = __expf(s[h] - mx); sum += ex[h]; }
    const float inv = 1.f / sum;
    f32x4 pv;
#pragma unroll
    for (int h = 0; h < 4; h++) pv[h] = __expf(ex[h] * inv);
    *(f32x4*)(p + (size_t)e * 4) = pv;
#pragma unroll
    for (int h = 0; h < 4; h++) atomicAdd(denom + (size_t)row * 4 + h, pv[h]);
}

// --- wave-autonomous head-split GEMM, v5.
//     Wave owns 32 edges x ALL 128 cols; iterates 8 col-blocks of 16 serially.
//     A: global->reg gather directly in MFMA frag layout (8 x 16B loads).
//     alpha: lane j computes edge j's alpha; intra-wave shuffles -> C-layout.
//     B: streamed from L2 per (cb,h) — small live set, remat-by-design.
//     ZERO LDS, ZERO barriers. 4 waves/SIMD via launch_bounds(256,4). ---
__global__ __launch_bounds__(256, 4) void k_gemm(
    const ushort_t* __restrict__ xbf, const int* __restrict__ ei,
    const float* __restrict__ p, const float* __restrict__ denom,
    const ushort_t* __restrict__ wbf, const float* __restrict__ bias,
    float* __restrict__ out)
{
    const int tid = threadIdx.x;
    const int lane = tid & 63;
    const int w = tid >> 6;
    const int et = blockIdx.x * 128 + w * 32;   // this wave's 32 edges

    // A fragments: direct global gather in MFMA layout
    int colr[2];
#pragma unroll
    for (int eb = 0; eb < 2; eb++)
        colr[eb] = ei[NE + et + eb * 16 + (lane & 15)];
    s16x8 af[2][4];
#pragma unroll
    for (int eb = 0; eb < 2; eb++) {
        const ushort_t* src = xbf + (size_t)colr[eb] * 128 + (lane >> 4) * 8;
#pragma unroll
        for (int ks = 0; ks < 4; ks++)
            af[eb][ks] = *(const s16x8*)(src + ks * 32);
    }

    // alpha: lane (j&31) computes edge et+j's f32x4; shuffle into C-layout vectors
    f32x4 alp;
    {
        const int e = et + (lane & 31);
        const int row = ei[e];
        const f32x4 pv = *(const f32x4*)(p + (size_t)e * 4);
        const f32x4 dv = *(const f32x4*)(denom + (size_t)row * 4);
        alp = pv / dv;
    }
    f32x4 av[4][2];
#pragma unroll
    for (int h = 0; h < 4; h++)
#pragma unroll
        for (int eb = 0; eb < 2; eb++)
#pragma unroll
            for (int r = 0; r < 4; r++)
                av[h][eb][r] = __shfl(alp[h], eb * 16 + (lane >> 4) * 4 + r, 64);

    const f32x4 zero = {0.f, 0.f, 0.f, 0.f};

#pragma unroll 1
    for (int cb = 0; cb < 8; cb++) {
        const int icol = cb * 16 + (lane & 15);
        const ushort_t* bbase = wbf + (size_t)icol * 512 + (lane >> 4) * 8;
        f32x4 fin0 = zero, fin1 = zero;
#pragma unroll
        for (int h = 0; h < 4; h++) {
            s16x8 bfr[4];
#pragma unroll
            for (int ks = 0; ks < 4; ks++)
                bfr[ks] = *(const s16x8*)(bbase + h * 128 + ks * 32);
            f32x4 a0 = __builtin_amdgcn_mfma_f32_16x16x32_bf16(af[0][0], bfr[0], zero, 0, 0, 0);
            f32x4 a1 = __builtin_amdgcn_mfma_f32_16x16x32_bf16(af[1][0], bfr[0], zero, 0, 0, 0);
#pragma unroll
            for (int ks = 1; ks < 4; ks++) {
                a0 = __builtin_amdgcn_mfma_f32_16x16x32_bf16(af[0][ks], bfr[ks], a0, 0, 0, 0);
                a1 = __builtin_amdgcn_mfma_f32_16x16x32_bf16(af[1][ks], bfr[ks], a1, 0, 0, 0);
            }
            fin0 += av[h][0] * a0;
            fin1 += av[h][1] * a1;
        }
        const float bias_r = bias[icol];
#pragma unroll
        for (int r = 0; r < 4; r++) {
            {
                const int e = et + (lane >> 4) * 4 + r;
                const size_t off = (size_t)e * 128 + icol;
                out[off] = fin0[r] + bias_r + bf2f(xbf[off]);
            }
            {
                const int e = et + 16 + (lane >> 4) * 4 + r;
                const size_t off = (size_t)e * 128 + icol;
                out[off] = fin1[r] + bias_r + bf2f(xbf[off]);
            }
        }
    }
}

extern "C" void kernel_launch(void* const* d_in, const int* in_sizes, int n_in,
                              void* d_out, int out_size, void* d_ws, size_t ws_size,
                              hipStream_t stream) {
    const float* x      = (const float*)d_in[0];
    const int*   ei_raw = (const int*)d_in[1];
    const float* att    = (const float*)d_in[2];
    const float* W      = (const float*)d_in[3];
    const float* b      = (const float*)d_in[4];
    float* out = (float*)d_out;

    char* ws = (char*)d_ws;
    float*    uv      = (float*)(ws);                     // N*8 f32   = 12.8 MB
    float*    p       = (float*)(ws + 12800000);          // E*4 f32   =  6.4 MB
    float*    denom   = (float*)(ws + 19200000);          // N*4 f32   =  6.4 MB
    ushort_t* wbf     = (ushort_t*)(ws + 32000000);       // 128 KB
    int*      flag    = (int*)(ws + 32200000);            // 4 B
    int*      ei32    = (int*)(ws + 32200064);            // 3.2 MB
    ushort_t* xbf     = (ushort_t*)(ws + 35400192);       // N*128 bf16 = 102.4 MB

    hipMemsetAsync(denom, 0, (size_t)NN * 4 * sizeof(float), stream);
    k_detect<<<1, 64, 0, stream>>>(ei_raw, flag);
    k_cvt_idx<<<2 * NE / 256, 256, 0, stream>>>(ei_raw, flag, ei32);
    k_wcvt<<<256, 256, 0, stream>>>(W, wbf);
    k_uv_cvt<<<2048, 256, 0, stream>>>(x, att, xbf, uv);
    k_edge<<<(NE + 255) / 256, 256, 0, stream>>>(ei32, uv, p, denom);
    k_gemm<<<NE / 128, 256, 0, stream>>>(xbf, ei32, p, denom, wbf, b, out);
}

// Round 9
// 279.744 us; speedup vs baseline: 1.4822x; 1.4822x over previous
//
#include <hip/hip_runtime.h>

#define NN 400000
#define NE 400000

typedef __attribute__((ext_vector_type(4))) float f32x4;
typedef __attribute__((ext_vector_type(8))) short s16x8;
typedef unsigned short ushort_t;

__device__ __forceinline__ ushort_t f2bf(float f) {
    union { float f; unsigned int u; } c;
    c.f = f;
    unsigned int u = c.u;
    u = u + 0x7fffu + ((u >> 16) & 1u);
    return (ushort_t)(u >> 16);
}
__device__ __forceinline__ float bf2f(ushort_t v) {
    union { unsigned int u; float f; } c;
    c.u = ((unsigned int)v) << 16;
    return c.f;
}

// --- detect whether edge_index arrived as int64 (odd 32-bit words all zero) ---
__global__ void k_detect(const int* __restrict__ ei_raw, int* __restrict__ flag) {
    if (threadIdx.x == 0 && blockIdx.x == 0) {
        int is64 = 1;
        for (int i = 0; i < 64; i++)
            if (ei_raw[2 * i + 1] != 0) { is64 = 0; break; }
        flag[0] = is64;
    }
}

__global__ void k_cvt_idx(const int* __restrict__ ei_raw, const int* __restrict__ flag,
                          int* __restrict__ ei32) {
    const int i = blockIdx.x * 256 + threadIdx.x;
    const int f = flag[0];
    ei32[i] = f ? ei_raw[2 * i] : ei_raw[i];
}

// --- W [128,512] f32 -> bf16, plain row-major ---
__global__ void k_wcvt(const float* __restrict__ W, ushort_t* __restrict__ wbf) {
    const int i = blockIdx.x * 256 + threadIdx.x;
    wbf[i] = f2bf(W[i]);
}

// --- fused: per-node u,v scores + x -> bf16 conversion (unchanged) ---
__global__ void k_uv_cvt(const float* __restrict__ x, const float* __restrict__ att,
                         ushort_t* __restrict__ xbf, float* __restrict__ uv) {
    const int lane = threadIdx.x & 63;
    const int wid = threadIdx.x >> 6;
    const int g = lane & 15;
    const int ns = lane >> 4;

    float areg[8][8];
#pragma unroll
    for (int h = 0; h < 4; h++) {
        const f32x4 fa = *(const f32x4*)(att + h * 256 + g * 8);
        const f32x4 fb = *(const f32x4*)(att + h * 256 + g * 8 + 4);
        const f32x4 ba = *(const f32x4*)(att + h * 256 + 128 + g * 8);
        const f32x4 bb = *(const f32x4*)(att + h * 256 + 128 + g * 8 + 4);
#pragma unroll
        for (int m = 0; m < 4; m++) {
            areg[h][m] = fa[m];     areg[h][4 + m] = fb[m];
            areg[4 + h][m] = ba[m]; areg[4 + h][4 + m] = bb[m];
        }
    }

    for (int tile = blockIdx.x; tile < NN / 32; tile += gridDim.x) {
        const int nb = tile * 32 + wid * 8 + ns;
#pragma unroll
        for (int t = 0; t < 2; t++) {
            const int n = nb + t * 4;
            const f32x4 xa = *(const f32x4*)(x + (size_t)n * 128 + g * 8);
            const f32x4 xb = *(const f32x4*)(x + (size_t)n * 128 + g * 8 + 4);
            s16x8 pk;
#pragma unroll
            for (int m = 0; m < 4; m++) { pk[m] = (short)f2bf(xa[m]); pk[4 + m] = (short)f2bf(xb[m]); }
            *(s16x8*)(xbf + (size_t)n * 128 + g * 8) = pk;
            float r[8];
#pragma unroll
            for (int v = 0; v < 8; v++) {
                float s = 0.f;
#pragma unroll
                for (int m = 0; m < 4; m++) s += xa[m] * areg[v][m];
#pragma unroll
                for (int m = 0; m < 4; m++) s += xb[m] * areg[v][4 + m];
                r[v] = s;
            }
#pragma unroll
            for (int mask = 1; mask <= 4; mask <<= 1)
#pragma unroll
                for (int v = 0; v < 8; v++) r[v] += __shfl_xor(r[v], mask, 64);
            const int gv = g & 7;
            float s = r[0];
#pragma unroll
            for (int v = 1; v < 8; v++) s = (gv == v) ? r[v] : s;
            s += __shfl_xor(s, 8, 64);
            if (g < 8) uv[(size_t)n * 8 + g] = s;
        }
    }
}

// --- per-edge: leaky_relu -> head softmax -> p=exp(score), atomic denom ---
__global__ void k_edge(const int* __restrict__ ei, const float* __restrict__ uv,
                       float* __restrict__ p, float* __restrict__ denom) {
    const int e = blockIdx.x * 256 + threadIdx.x;
    if (e >= NE) return;
    const int row = ei[e];
    const int col = ei[NE + e];
    const f32x4 u = *(const f32x4*)(uv + (size_t)row * 8);
    const f32x4 v = *(const f32x4*)(uv + (size_t)col * 8 + 4);
    float s[4];
    float mx = -1e30f;
#pragma unroll
    for (int h = 0; h < 4; h++) {
        float t = u[h] + v[h];
        t = t > 0.f ? t : 0.01f * t;
        s[h] = t;
        mx = fmaxf(mx, t);
    }
    float ex[4], sum = 0.f;
#pragma unroll
    for (int h = 0; h < 4; h++) { ex[h] = __expf(s[h] - mx); sum += ex[h]; }
    const float inv = 1.f / sum;
    f32x4 pv;
#pragma unroll
    for (int h = 0; h < 4; h++) pv[h] = __expf(ex[h] * inv);
    *(f32x4*)(p + (size_t)e * 4) = pv;
#pragma unroll
    for (int h = 0; h < 4; h++) atomicAdd(denom + (size_t)row * 4 + h, pv[h]);
}

// --- persistent head-split GEMM, v6.
//     Grid = 256 blocks (1/CU), 8 waves. W (128KB bf16) staged ONCE into LDS
//     (swizzled). Grid-stride over 64-edge tiles: A staged via global_load_lds
//     (source-side swizzle, r6-proven), alpha inline (1KB LDS), 2 barriers/tile.
//     Wave = 32 edges x 32 cols (eg2 x cg4). A-frags h-invariant, held in 32 VGPR;
//     B-frags re-read from LDS per head — remat-safe BY DESIGN (LDS, not L2). ---
__global__ __launch_bounds__(512, 2) void k_gemm(
    const ushort_t* __restrict__ xbf, const int* __restrict__ ei,
    const float* __restrict__ p, const float* __restrict__ denom,
    const ushort_t* __restrict__ wbf, const float* __restrict__ bias,
    float* __restrict__ out)
{
    __shared__ __align__(16) ushort_t Bsm[128 * 512];  // 128KB [icol][k], swz ((icol&7)<<4)
    __shared__ __align__(16) ushort_t Asm[64 * 128];   // 16KB  [e][k],    swz ((e&15)<<4)
    __shared__ __align__(16) float alp_s[4][64];

    const int tid = threadIdx.x;
    const int lane = tid & 63;
    const int w = tid >> 6;
    const int eg = w & 1;        // edge group: rows eg*32..+32
    const int cg = w >> 1;       // col group:  cols cg*32..+32

    // stage W once: thread t -> icol = t>>2, quarter q = t&3 (256B), swizzled ds_write
    {
        const int icol = tid >> 2, q = tid & 3;
        const ushort_t* src = wbf + icol * 512 + q * 128;
#pragma unroll
        for (int m = 0; m < 16; m++) {
            const s16x8 v = *(const s16x8*)(src + m * 8);
            const int lb = q * 256 + m * 16;
            const int byte = icol * 1024 + (lb ^ ((icol & 7) << 4));
            *(s16x8*)((char*)Bsm + byte) = v;
        }
    }
    float bias_r[2];
#pragma unroll
    for (int cbi = 0; cbi < 2; cbi++) bias_r[cbi] = bias[cg * 32 + cbi * 16 + (lane & 15)];

    const f32x4 zero = {0.f, 0.f, 0.f, 0.f};
    const int ntiles = NE / 64;

#pragma unroll 1
    for (int tile = blockIdx.x; tile < ntiles; tile += gridDim.x) {
        __syncthreads();   // prev tile's reads done (and W visible on first iter)
        // A stage: 2 async global_load_lds per thread, source-side swizzle
#pragma unroll
        for (int i = 0; i < 2; i++) {
            const int rr = w * 8 + i * 4 + (lane >> 4);
            const int col = ei[NE + tile * 64 + rr];
            const int c = (lane & 15) ^ (rr & 15);
            const ushort_t* src = xbf + (size_t)col * 128 + c * 8;
            __builtin_amdgcn_global_load_lds(
                (const __attribute__((address_space(1))) unsigned int*)src,
                (__attribute__((address_space(3))) unsigned int*)((char*)Asm + w * 2048 + i * 1024),
                16, 0, 0);
        }
        // alpha inline
        if (tid < 64) {
            const int e = tile * 64 + tid;
            const int row = ei[e];
            const f32x4 pv = *(const f32x4*)(p + (size_t)e * 4);
            const f32x4 dv = *(const f32x4*)(denom + (size_t)row * 4);
#pragma unroll
            for (int h = 0; h < 4; h++) alp_s[h][tid] = pv[h] / dv[h];
        }
        __syncthreads();   // A + alpha ready

        // A fragments: h-invariant, read once, held (32 VGPR)
        s16x8 af[2][4];
#pragma unroll
        for (int eb = 0; eb < 2; eb++) {
            const int rr = eg * 32 + eb * 16 + (lane & 15);
#pragma unroll
            for (int ks = 0; ks < 4; ks++) {
                const int byte = rr * 256 + ((ks * 64 + (lane >> 4) * 16) ^ ((rr & 15) << 4));
                af[eb][ks] = *(const s16x8*)((const char*)Asm + byte);
            }
        }

        f32x4 fin[2][2];
#pragma unroll
        for (int eb = 0; eb < 2; eb++)
#pragma unroll
            for (int cbi = 0; cbi < 2; cbi++) fin[eb][cbi] = zero;

#pragma unroll
        for (int h = 0; h < 4; h++) {
            s16x8 bfr[2][4];
#pragma unroll
            for (int cbi = 0; cbi < 2; cbi++) {
                const int icol = cg * 32 + cbi * 16 + (lane & 15);
#pragma unroll
                for (int ks = 0; ks < 4; ks++) {
                    const int byte = icol * 1024 +
                        ((h * 256 + ks * 64 + (lane >> 4) * 16) ^ ((icol & 7) << 4));
                    bfr[cbi][ks] = *(const s16x8*)((const char*)Bsm + byte);
                }
            }
            f32x4 av[2];
#pragma unroll
            for (int eb = 0; eb < 2; eb++)
                av[eb] = *(const f32x4*)&alp_s[h][eg * 32 + eb * 16 + (lane >> 4) * 4];
#pragma unroll
            for (int eb = 0; eb < 2; eb++)
#pragma unroll
                for (int cbi = 0; cbi < 2; cbi++) {
                    f32x4 a = __builtin_amdgcn_mfma_f32_16x16x32_bf16(af[eb][0], bfr[cbi][0], zero, 0, 0, 0);
#pragma unroll
                    for (int ks = 1; ks < 4; ks++)
                        a = __builtin_amdgcn_mfma_f32_16x16x32_bf16(af[eb][ks], bfr[cbi][ks], a, 0, 0, 0);
                    fin[eb][cbi] += av[eb] * a;
                }
        }
        // epilogue: + bias + residual
#pragma unroll
        for (int eb = 0; eb < 2; eb++)
#pragma unroll
            for (int cbi = 0; cbi < 2; cbi++) {
                const int icol = cg * 32 + cbi * 16 + (lane & 15);
#pragma unroll
                for (int r = 0; r < 4; r++) {
                    const int e = tile * 64 + eg * 32 + eb * 16 + (lane >> 4) * 4 + r;
                    const size_t off = (size_t)e * 128 + icol;
                    out[off] = fin[eb][cbi][r] + bias_r[cbi] + bf2f(xbf[off]);
                }
            }
    }
}

extern "C" void kernel_launch(void* const* d_in, const int* in_sizes, int n_in,
                              void* d_out, int out_size, void* d_ws, size_t ws_size,
                              hipStream_t stream) {
    const float* x      = (const float*)d_in[0];
    const int*   ei_raw = (const int*)d_in[1];
    const float* att    = (const float*)d_in[2];
    const float* W      = (const float*)d_in[3];
    const float* b      = (const float*)d_in[4];
    float* out = (float*)d_out;

    char* ws = (char*)d_ws;
    float*    uv      = (float*)(ws);                     // N*8 f32   = 12.8 MB
    float*    p       = (float*)(ws + 12800000);          // E*4 f32   =  6.4 MB
    float*    denom   = (float*)(ws + 19200000);          // N*4 f32   =  6.4 MB
    ushort_t* wbf     = (ushort_t*)(ws + 32000000);       // 128 KB
    int*      flag    = (int*)(ws + 32200000);            // 4 B
    int*      ei32    = (int*)(ws + 32200064);            // 3.2 MB
    ushort_t* xbf     = (ushort_t*)(ws + 35400192);       // N*128 bf16 = 102.4 MB

    hipMemsetAsync(denom, 0, (size_t)NN * 4 * sizeof(float), stream);
    k_detect<<<1, 64, 0, stream>>>(ei_raw, flag);
    k_cvt_idx<<<2 * NE / 256, 256, 0, stream>>>(ei_raw, flag, ei32);
    k_wcvt<<<256, 256, 0, stream>>>(W, wbf);
    k_uv_cvt<<<2048, 256, 0, stream>>>(x, att, xbf, uv);
    k_edge<<<(NE + 255) / 256, 256, 0, stream>>>(ei32, uv, p, denom);
    k_gemm<<<256, 512, 0, stream>>>(xbf, ei32, p, denom, wbf, b, out);
}